// Round 5
// baseline (3768.248 us; speedup 1.0000x reference)
//
#include <hip/hip_runtime.h>
#include <hip/hip_fp16.h>

#define NB 2048
#define NT 60
#define NDL 100
#define ND 512
#define NH 256
#define NG 768

typedef const float* __restrict__ fpp;

// ---------------------------------------------------------------------------
// fc GEMM: C[m][n] = sum_k A[m][k]*B[n][k] + bias[n];  all fp32.
// ---------------------------------------------------------------------------
__global__ __launch_bounds__(256) void gemm_fc(
    fpp A, fpp Bm, fpp bias, float* __restrict__ C,
    int M, int N, int K, int lda, int ldb, int ldc)
{
  __shared__ float As[16][68];
  __shared__ float Bs[16][68];
  const int bm = blockIdx.x * 64, bn = blockIdx.y * 64;
  const int tid = threadIdx.x;
  const int tx = tid & 15, ty = tid >> 4;
  float acc[4][4] = {};
  for (int k0 = 0; k0 < K; k0 += 16) {
#pragma unroll
    for (int i = 0; i < 4; i++) {
      int e = tid + i * 256;
      int m = e >> 4, k = e & 15;
      As[k][m] = (k0 + k < K) ? A[(size_t)(bm + m) * lda + k0 + k] : 0.f;
      Bs[k][m] = (k0 + k < K) ? Bm[(size_t)(bn + m) * ldb + k0 + k] : 0.f;
    }
    __syncthreads();
#pragma unroll
    for (int kk = 0; kk < 16; kk++) {
      float4 av = *(const float4*)&As[kk][ty * 4];
      float4 bv = *(const float4*)&Bs[kk][tx * 4];
      float a_[4] = {av.x, av.y, av.z, av.w};
      float b_[4] = {bv.x, bv.y, bv.z, bv.w};
#pragma unroll
      for (int i = 0; i < 4; i++)
#pragma unroll
        for (int j = 0; j < 4; j++)
          acc[i][j] = fmaf(a_[i], b_[j], acc[i][j]);
    }
    __syncthreads();
  }
#pragma unroll
  for (int i = 0; i < 4; i++) {
    int m = bm + ty * 4 + i;
#pragma unroll
    for (int j = 0; j < 4; j++) {
      int n = bn + tx * 4 + j;
      C[(size_t)m * ldc + n] = acc[i][j] + bias[n];
    }
  }
}

// ---------------------------------------------------------------------------
// BatchNorm batch statistics -> per-column scale/shift
// ---------------------------------------------------------------------------
__global__ __launch_bounds__(256) void bn_stats(
    const float* __restrict__ h0, fpp g, fpp b,
    float* __restrict__ scale, float* __restrict__ shift)
{
  const int cl = threadIdx.x & 31;
  const int col = blockIdx.x * 32 + cl;
  const int row0 = threadIdx.x >> 5;  // 0..7
  float s1 = 0.f, s2 = 0.f;
  for (int r = row0; r < NB; r += 8) {
    float v = h0[(size_t)r * ND + col];
    s1 += v; s2 += v * v;
  }
  __shared__ float l1[8][33], l2[8][33];
  l1[row0][cl] = s1;
  l2[row0][cl] = s2;
  __syncthreads();
  if (row0 == 0) {
#pragma unroll
    for (int r = 1; r < 8; r++) { s1 += l1[r][cl]; s2 += l2[r][cl]; }
    float mu = s1 / NB;
    float var = s2 / NB - mu * mu;
    float sc = g[col] * rsqrtf(var + 1e-5f);
    scale[col] = sc;
    shift[col] = b[col] - mu * sc;
  }
}

__global__ void bn_lrelu(float* __restrict__ h, const float* __restrict__ scale,
                         const float* __restrict__ shift)
{
  int idx = blockIdx.x * 256 + threadIdx.x;
  int d = idx & (ND - 1);
  float v = h[idx] * scale[d] + shift[d];
  h[idx] = (v >= 0.f) ? v : 0.2f * v;
}

// ---------------------------------------------------------------------------
// One GRU time step, both directions (blockIdx.z), 3 gates fused.
// fp32 state ping-pong (hprev -> hnext, [B,512]; fwd cols 0..255, bwd 256..511)
// plus fp16 write into the materialized sequence gru_seq [B,T,512].
// (|h| < 1 always, so fp16 is safe and 8x more precise than bf16.)
// ---------------------------------------------------------------------------
__global__ __launch_bounds__(256) void gru_step(
    const float* __restrict__ xg_f, const float* __restrict__ xg_b,
    fpp Whh_f, fpp Whh_b, fpp bhh_f, fpp bhh_b,
    const float* __restrict__ hprev, float* __restrict__ hnext,
    __half* __restrict__ seq, int step)
{
  const int dir = blockIdx.z;
  const float* __restrict__ xg = dir ? xg_b : xg_f;
  fpp Whh = dir ? Whh_b : Whh_f;
  fpp bhh = dir ? bhh_b : bhh_f;
  const int t_out = dir ? (NT - 1 - step) : step;
  const int dcol = dir * NH;
  const int bm = blockIdx.x * 64, bn = blockIdx.y * 64;
  const int tid = threadIdx.x, tx = tid & 15, ty = tid >> 4;

  __shared__ float As[16][68];
  __shared__ float Bs[3][16][68];
  float aR[4][4] = {}, aZ[4][4] = {}, aN[4][4] = {};

  for (int k0 = 0; k0 < NH; k0 += 16) {
#pragma unroll
    for (int i = 0; i < 4; i++) {
      int e = tid + i * 256; int m = e >> 4, k = e & 15;
      As[k][m] = (step == 0) ? 0.f
               : hprev[(size_t)(bm + m) * ND + dcol + k0 + k];
    }
#pragma unroll
    for (int i = 0; i < 12; i++) {
      int e = tid + i * 256;
      int g = e >> 10, rem = e & 1023;
      int n = rem >> 4, k = rem & 15;
      Bs[g][k][n] = Whh[(size_t)(g * NH + bn + n) * NH + k0 + k];
    }
    __syncthreads();
#pragma unroll
    for (int kk = 0; kk < 16; kk++) {
      float4 av = *(const float4*)&As[kk][ty * 4];
      float4 bR = *(const float4*)&Bs[0][kk][tx * 4];
      float4 bZ = *(const float4*)&Bs[1][kk][tx * 4];
      float4 bN = *(const float4*)&Bs[2][kk][tx * 4];
      float a_[4] = {av.x, av.y, av.z, av.w};
      float r_[4] = {bR.x, bR.y, bR.z, bR.w};
      float z_[4] = {bZ.x, bZ.y, bZ.z, bZ.w};
      float n_[4] = {bN.x, bN.y, bN.z, bN.w};
#pragma unroll
      for (int i = 0; i < 4; i++)
#pragma unroll
        for (int j = 0; j < 4; j++) {
          aR[i][j] = fmaf(a_[i], r_[j], aR[i][j]);
          aZ[i][j] = fmaf(a_[i], z_[j], aZ[i][j]);
          aN[i][j] = fmaf(a_[i], n_[j], aN[i][j]);
        }
    }
    __syncthreads();
  }

#pragma unroll
  for (int i = 0; i < 4; i++) {
    int b = bm + ty * 4 + i;
#pragma unroll
    for (int j = 0; j < 4; j++) {
      int n = bn + tx * 4 + j;
      float ghr = aR[i][j] + bhh[n];
      float ghz = aZ[i][j] + bhh[NH + n];
      float ghn = aN[i][j] + bhh[2 * NH + n];
      float xr = xg[(size_t)b * NG + n];
      float xz = xg[(size_t)b * NG + NH + n];
      float xn = xg[(size_t)b * NG + 2 * NH + n];
      float r = 1.f / (1.f + __expf(-(xr + ghr)));
      float z = 1.f / (1.f + __expf(-(xz + ghz)));
      float nn = tanhf(xn + r * ghn);
      float hp = (step == 0) ? 0.f : hprev[(size_t)b * ND + dcol + n];
      float hn = (1.f - z) * nn + z * hp;
      hnext[(size_t)b * ND + dcol + n] = hn;
      seq[((size_t)b * NT + t_out) * ND + dcol + n] = __float2half(hn);
    }
  }
}

// ---------------------------------------------------------------------------
// Attention scores: score[bt] = sum_h W2[h] * tanh(seq[bt]@W1[h] + b1[h])
// ---------------------------------------------------------------------------
__global__ __launch_bounds__(256) void attn_score(
    const __half* __restrict__ seq, fpp W1, fpp b1, fpp W2,
    float* __restrict__ scores)
{
  __shared__ float As[16][68];
  __shared__ float Bs[16][68];
  const int bm = blockIdx.x * 64, bn = blockIdx.y * 64;
  const int tid = threadIdx.x, tx = tid & 15, ty = tid >> 4;
  float acc[4][4] = {};
  for (int k0 = 0; k0 < ND; k0 += 16) {
#pragma unroll
    for (int i = 0; i < 4; i++) {
      int e = tid + i * 256; int m = e >> 4, k = e & 15;
      As[k][m] = __half2float(seq[(size_t)(bm + m) * ND + k0 + k]);
      Bs[k][m] = W1[(size_t)(bn + m) * ND + k0 + k];
    }
    __syncthreads();
#pragma unroll
    for (int kk = 0; kk < 16; kk++) {
      float4 av = *(const float4*)&As[kk][ty * 4];
      float4 bv = *(const float4*)&Bs[kk][tx * 4];
      float a_[4] = {av.x, av.y, av.z, av.w};
      float b_[4] = {bv.x, bv.y, bv.z, bv.w};
#pragma unroll
      for (int i = 0; i < 4; i++)
#pragma unroll
        for (int j = 0; j < 4; j++)
          acc[i][j] = fmaf(a_[i], b_[j], acc[i][j]);
    }
    __syncthreads();
  }
#pragma unroll
  for (int i = 0; i < 4; i++) {
    float rs = 0.f;
#pragma unroll
    for (int j = 0; j < 4; j++) {
      int n = bn + tx * 4 + j;
      rs += tanhf(acc[i][j] + b1[n]) * W2[n];
    }
    rs += __shfl_down(rs, 8, 16);
    rs += __shfl_down(rs, 4, 16);
    rs += __shfl_down(rs, 2, 16);
    rs += __shfl_down(rs, 1, 16);
    if (tx == 0) atomicAdd(&scores[bm + ty * 4 + i], rs);
  }
}

__global__ void zero_scores(float* __restrict__ s)
{
  s[blockIdx.x * 256 + threadIdx.x] = 0.f;
}

__global__ void softmax_t(float* __restrict__ s)
{
  int b = blockIdx.x, lane = threadIdx.x;
  float v = (lane < NT) ? s[(size_t)b * NT + lane] : -1e30f;
  float m = v;
#pragma unroll
  for (int off = 32; off >= 1; off >>= 1) m = fmaxf(m, __shfl_xor(m, off));
  float e = (lane < NT) ? __expf(v - m) : 0.f;
  float sum = e;
#pragma unroll
  for (int off = 32; off >= 1; off >>= 1) sum += __shfl_xor(sum, off);
  if (lane < NT) s[(size_t)b * NT + lane] = e / sum;
}

__global__ void context_c(const __half* __restrict__ seq,
                          const float* __restrict__ w, float* __restrict__ c)
{
  int idx = blockIdx.x * 256 + threadIdx.x;  // over NB*128 groups of 4 cols
  int b = idx >> 7, d4 = (idx & 127) * 4;
  float s0 = 0.f, s1 = 0.f, s2 = 0.f, s3 = 0.f;
  for (int t = 0; t < NT; t++) {
    float wt = w[(size_t)b * NT + t];
    const __half* p = seq + ((size_t)b * NT + t) * ND + d4;
    s0 += wt * __half2float(p[0]);
    s1 += wt * __half2float(p[1]);
    s2 += wt * __half2float(p[2]);
    s3 += wt * __half2float(p[3]);
  }
  float* cp = c + (size_t)b * ND + d4;
  cp[0] = s0; cp[1] = s1; cp[2] = s2; cp[3] = s3;
}

// ---------------------------------------------------------------------------
// Fused joints projection + forward kinematics. One wave per (b,t).
// ---------------------------------------------------------------------------
__constant__ float c_lower[6] = {-3.1416f, -1.5708f, -3.1416f, -2.6f, -1.5708f, -1.2f};
__constant__ float c_upper[6] = { 3.1416f,  1.5708f,  3.1416f,  0.1f,  1.5708f,  1.2f};

__global__ __launch_bounds__(256) void joints_fk(
    const __half* __restrict__ seq, const float* __restrict__ c,
    fpp jW, fpp jb, float* __restrict__ out)
{
  __shared__ float w[6 * ND];
  const int tid = threadIdx.x;
#pragma unroll
  for (int i = 0; i < 12; i++) w[tid + i * 256] = jW[tid + i * 256];
  __syncthreads();

  const int wave = tid >> 6, lane = tid & 63;
  const int bt = blockIdx.x * 4 + wave;
  const int b = bt / NT;
  const int d0 = lane * 8;

  float xv[8];
#pragma unroll
  for (int i = 0; i < 8; i++)
    xv[i] = __half2float(seq[(size_t)bt * ND + d0 + i]) + c[(size_t)b * ND + d0 + i];

  float jnt[6];
#pragma unroll
  for (int j = 0; j < 6; j++) {
    float p = 0.f;
#pragma unroll
    for (int i = 0; i < 8; i++) p = fmaf(xv[i], w[j * ND + d0 + i], p);
#pragma unroll
    for (int off = 32; off >= 1; off >>= 1) p += __shfl_xor(p, off);
    jnt[j] = p + jb[j];
  }

  float th[6];
#pragma unroll
  for (int j = 0; j < 6; j++)
    th[j] = jnt[j] * (c_upper[j] - c_lower[j]) + c_lower[j];

  float c0x = 1.f, c0y = 0.f, c0z = 0.f;
  float c1x = 0.f, c1y = 1.f, c1z = 0.f;
  float c2x = 0.f, c2y = 0.f, c2z = 1.f;
  float px = 0.f, py = 0.f, pz = 0.1f;
  float s, cc, tx_, ty_, tz_, ux_, uy_, uz_;

  // rotZ(th0)
  s = sinf(th[0]); cc = cosf(th[0]);
  tx_ = cc * c0x + s * c1x; ty_ = cc * c0y + s * c1y; tz_ = cc * c0z + s * c1z;
  ux_ = -s * c0x + cc * c1x; uy_ = -s * c0y + cc * c1y; uz_ = -s * c0z + cc * c1z;
  c0x = tx_; c0y = ty_; c0z = tz_; c1x = ux_; c1y = uy_; c1z = uz_;

  float shx = px, shy = py, shz = pz;  // shoulder2
  // rotX(th1)
  s = sinf(th[1]); cc = cosf(th[1]);
  tx_ = cc * c1x + s * c2x; ty_ = cc * c1y + s * c2y; tz_ = cc * c1z + s * c2z;
  ux_ = -s * c1x + cc * c2x; uy_ = -s * c1y + cc * c2y; uz_ = -s * c1z + cc * c2z;
  c1x = tx_; c1y = ty_; c1z = tz_; c2x = ux_; c2y = uy_; c2z = uz_;

  // rotY(th2)
  s = sinf(th[2]); cc = cosf(th[2]);
  tx_ = cc * c0x - s * c2x; ty_ = cc * c0y - s * c2y; tz_ = cc * c0z - s * c2z;
  ux_ = s * c0x + cc * c2x; uy_ = s * c0y + cc * c2y; uz_ = s * c0z + cc * c2z;
  c0x = tx_; c0y = ty_; c0z = tz_; c2x = ux_; c2y = uy_; c2z = uz_;

  // joint3 offset -> forearm
  px -= 0.25f * c1x; py -= 0.25f * c1y; pz -= 0.25f * c1z;
  float fox = px, foy = py, foz = pz;
  // rotX(th3)
  s = sinf(th[3]); cc = cosf(th[3]);
  tx_ = cc * c1x + s * c2x; ty_ = cc * c1y + s * c2y; tz_ = cc * c1z + s * c2z;
  ux_ = -s * c1x + cc * c2x; uy_ = -s * c1y + cc * c2y; uz_ = -s * c1z + cc * c2z;
  c1x = tx_; c1y = ty_; c1z = tz_; c2x = ux_; c2y = uy_; c2z = uz_;

  // rotY(th4)
  s = sinf(th[4]); cc = cosf(th[4]);
  tx_ = cc * c0x - s * c2x; ty_ = cc * c0y - s * c2y; tz_ = cc * c0z - s * c2z;
  ux_ = s * c0x + cc * c2x; uy_ = s * c0y + cc * c2y; uz_ = s * c0z + cc * c2z;
  c0x = tx_; c0y = ty_; c0z = tz_; c2x = ux_; c2y = uy_; c2z = uz_;

  // joint5 offset -> wrist
  px -= 0.25f * c1x; py -= 0.25f * c1y; pz -= 0.25f * c1z;
  float wx = px, wy = py, wz = pz;
  // rotX(th5)
  s = sinf(th[5]); cc = cosf(th[5]);
  tx_ = cc * c1x + s * c2x; ty_ = cc * c1y + s * c2y; tz_ = cc * c1z + s * c2z;
  ux_ = -s * c1x + cc * c2x; uy_ = -s * c1y + cc * c2y; uz_ = -s * c1z + cc * c2z;
  c1x = tx_; c1y = ty_; c1z = tz_; c2x = ux_; c2y = uy_; c2z = uz_;

  float f1x = wx - 0.08f * c1x + 0.02f * c2x;
  float f1y = wy - 0.08f * c1y + 0.02f * c2y;
  float f1z = wz - 0.08f * c1z + 0.02f * c2z;
  float f4x = wx - 0.08f * c1x - 0.02f * c2x;
  float f4y = wy - 0.08f * c1y - 0.02f * c2y;
  float f4z = wz - 0.08f * c1z - 0.02f * c2z;

  float dsx = shx - fox, dsy = shy - foy, dsz = shz - foz;
  float dwx = wx - fox, dwy = wy - foy, dwz = wz - foz;
  float bodyL = 0.5f * (sqrtf(dsx * dsx + dsy * dsy + dsz * dsz) +
                        sqrtf(dwx * dwx + dwy * dwy + dwz * dwz));
  float inv = 1.f / bodyL;

  float rel[9];
  rel[0] = (wx - shx) * inv; rel[1] = (wy - shy) * inv; rel[2] = (wz - shz) * inv;
  rel[3] = (f1x - shx) * inv; rel[4] = (f1y - shy) * inv; rel[5] = (f1z - shz) * inv;
  rel[6] = (f4x - shx) * inv; rel[7] = (f4y - shy) * inv; rel[8] = (f4z - shz) * inv;

  if (lane < 9) out[(size_t)bt * 9 + lane] = rel[lane];
}

// ---------------------------------------------------------------------------
extern "C" void kernel_launch(void* const* d_in, const int* in_sizes, int n_in,
                              void* d_out, int out_size, void* d_ws, size_t ws_size,
                              hipStream_t stream)
{
  fpp z     = (fpp)d_in[0];
  fpp W_fc  = (fpp)d_in[1];
  fpp b_fc  = (fpp)d_in[2];
  fpp bn_g  = (fpp)d_in[3];
  fpp bn_b  = (fpp)d_in[4];
  fpp Wih_f = (fpp)d_in[5];
  fpp Whh_f = (fpp)d_in[6];
  fpp bih_f = (fpp)d_in[7];
  fpp bhh_f = (fpp)d_in[8];
  fpp Wih_b = (fpp)d_in[9];
  fpp Whh_b = (fpp)d_in[10];
  fpp bih_b = (fpp)d_in[11];
  fpp bhh_b = (fpp)d_in[12];
  fpp aW1   = (fpp)d_in[13];
  fpp ab1   = (fpp)d_in[14];
  fpp aW2   = (fpp)d_in[15];
  fpp jW    = (fpp)d_in[16];
  fpp jb    = (fpp)d_in[17];

  // fp32 region (~34.5 MB), then fp16 sequence (~126 MB). Total ~160 MB.
  float* ws     = (float*)d_ws;
  float* h      = ws;                        // 2048*512   (4 MB)
  float* xg_f   = h + 1048576;               // 2048*768   (6 MB)
  float* xg_b   = xg_f + 1572864;            // 2048*768   (6 MB)
  float* scale  = xg_b + 1572864;            // 512
  float* shift  = scale + 512;               // 512
  float* scores = shift + 512;               // 2048*60    (0.5 MB)
  float* cbuf   = scores + 122880;           // 2048*512   (4 MB)
  float* hst0   = cbuf + 1048576;            // 2048*512   (4 MB)
  float* hst1   = hst0 + 1048576;            // 2048*512   (4 MB)
  __half* gseq  = (__half*)(hst1 + 1048576); // 2048*60*512 fp16 (126 MB)

  // 1. fc: h0 = z @ W_fc^T + b_fc
  gemm_fc<<<dim3(32, 8), 256, 0, stream>>>(z, W_fc, b_fc, h,
                                           NB, ND, NDL, NDL, NDL, ND);
  // 2. batchnorm (training stats) + leaky relu, in place
  bn_stats<<<16, 256, 0, stream>>>(h, bn_g, bn_b, scale, shift);
  bn_lrelu<<<4096, 256, 0, stream>>>(h, scale, shift);
  // 3. time-invariant input projections (computed ONCE, not per timestep)
  gemm_fc<<<dim3(32, 12), 256, 0, stream>>>(h, Wih_f, bih_f, xg_f,
                                            NB, NG, ND, ND, ND, NG);
  gemm_fc<<<dim3(32, 12), 256, 0, stream>>>(h, Wih_b, bih_b, xg_b,
                                            NB, NG, ND, ND, ND, NG);
  // 4. GRU recurrence, both directions per launch, fp32 state ping-pong
  for (int s = 0; s < NT; s++) {
    float* hp = (s & 1) ? hst1 : hst0;
    float* hn = (s & 1) ? hst0 : hst1;
    gru_step<<<dim3(32, 4, 2), 256, 0, stream>>>(xg_f, xg_b, Whh_f, Whh_b,
                                                 bhh_f, bhh_b, hp, hn, gseq, s);
  }
  // 5. attention
  zero_scores<<<480, 256, 0, stream>>>(scores);
  attn_score<<<dim3(1920, 4), 256, 0, stream>>>(gseq, aW1, ab1, aW2, scores);
  softmax_t<<<NB, 64, 0, stream>>>(scores);
  context_c<<<1024, 256, 0, stream>>>(gseq, scores, cbuf);
  // 6. joints projection + forward kinematics, fused
  joints_fk<<<30720, 256, 0, stream>>>(gseq, cbuf, jW, jb, (float*)d_out);
}

// Round 6
// 1402.296 us; speedup vs baseline: 2.6872x; 2.6872x over previous
//
#include <hip/hip_runtime.h>
#include <hip/hip_fp16.h>

#define NB 2048
#define NT 60
#define NDL 100
#define ND 512
#define NH 256
#define NG 768

typedef const float* __restrict__ fpp;
typedef _Float16 half8 __attribute__((ext_vector_type(8)));
typedef float floatx4 __attribute__((ext_vector_type(4)));

// ---------------------------------------------------------------------------
// fp32 tiled GEMM (used for fc + input projections): C = A*B^T + bias
// ---------------------------------------------------------------------------
__global__ __launch_bounds__(256) void gemm_fc(
    fpp A, fpp Bm, fpp bias, float* __restrict__ C,
    int M, int N, int K, int lda, int ldb, int ldc)
{
  __shared__ float As[16][68];
  __shared__ float Bs[16][68];
  const int bm = blockIdx.x * 64, bn = blockIdx.y * 64;
  const int tid = threadIdx.x;
  const int tx = tid & 15, ty = tid >> 4;
  float acc[4][4] = {};
  for (int k0 = 0; k0 < K; k0 += 16) {
#pragma unroll
    for (int i = 0; i < 4; i++) {
      int e = tid + i * 256;
      int m = e >> 4, k = e & 15;
      As[k][m] = (k0 + k < K) ? A[(size_t)(bm + m) * lda + k0 + k] : 0.f;
      Bs[k][m] = (k0 + k < K) ? Bm[(size_t)(bn + m) * ldb + k0 + k] : 0.f;
    }
    __syncthreads();
#pragma unroll
    for (int kk = 0; kk < 16; kk++) {
      float4 av = *(const float4*)&As[kk][ty * 4];
      float4 bv = *(const float4*)&Bs[kk][tx * 4];
      float a_[4] = {av.x, av.y, av.z, av.w};
      float b_[4] = {bv.x, bv.y, bv.z, bv.w};
#pragma unroll
      for (int i = 0; i < 4; i++)
#pragma unroll
        for (int j = 0; j < 4; j++)
          acc[i][j] = fmaf(a_[i], b_[j], acc[i][j]);
    }
    __syncthreads();
  }
#pragma unroll
  for (int i = 0; i < 4; i++) {
    int m = bm + ty * 4 + i;
#pragma unroll
    for (int j = 0; j < 4; j++) {
      int n = bn + tx * 4 + j;
      C[(size_t)m * ldc + n] = acc[i][j] + bias[n];
    }
  }
}

// ---------------------------------------------------------------------------
// BatchNorm batch statistics -> per-column scale/shift
// ---------------------------------------------------------------------------
__global__ __launch_bounds__(256) void bn_stats(
    const float* __restrict__ h0, fpp g, fpp b,
    float* __restrict__ scale, float* __restrict__ shift)
{
  const int cl = threadIdx.x & 31;
  const int col = blockIdx.x * 32 + cl;
  const int row0 = threadIdx.x >> 5;
  float s1 = 0.f, s2 = 0.f;
  for (int r = row0; r < NB; r += 8) {
    float v = h0[(size_t)r * ND + col];
    s1 += v; s2 += v * v;
  }
  __shared__ float l1[8][33], l2[8][33];
  l1[row0][cl] = s1;
  l2[row0][cl] = s2;
  __syncthreads();
  if (row0 == 0) {
#pragma unroll
    for (int r = 1; r < 8; r++) { s1 += l1[r][cl]; s2 += l2[r][cl]; }
    float mu = s1 / NB;
    float var = s2 / NB - mu * mu;
    float sc = g[col] * rsqrtf(var + 1e-5f);
    scale[col] = sc;
    shift[col] = b[col] - mu * sc;
  }
}

__global__ void bn_lrelu(float* __restrict__ h, const float* __restrict__ scale,
                         const float* __restrict__ shift)
{
  int idx = blockIdx.x * 256 + threadIdx.x;
  int d = idx & (ND - 1);
  float v = h[idx] * scale[d] + shift[d];
  h[idx] = (v >= 0.f) ? v : 0.2f * v;
}

// ---------------------------------------------------------------------------
// One-time weight conversion fp32 -> fp16 (Whh_f, Whh_b, attn W1)
// ---------------------------------------------------------------------------
__global__ void convert_w(fpp Whh_f, fpp Whh_b, fpp W1,
                          __half* __restrict__ wf, __half* __restrict__ wb,
                          __half* __restrict__ w1)
{
  int idx = blockIdx.x * 256 + threadIdx.x;        // 0 .. 524287
  if (idx < 196608) wf[idx] = __float2half(Whh_f[idx]);
  else if (idx < 393216) wb[idx - 196608] = __float2half(Whh_b[idx - 196608]);
  else w1[idx - 393216] = __float2half(W1[idx - 393216]);
}

// ---------------------------------------------------------------------------
// GRU step via MFMA 16x16x32 f16. A = seq[t_in] (fp16), B = Whh fp16.
// Block: 256 thr (4 waves), BM=64 rows, BN=64 hidden cols, all 3 gates.
// State update in fp32 (hst ping-pong); seq written fp16.
// ---------------------------------------------------------------------------
__global__ __launch_bounds__(256) void gru_step_mfma(
    const float* __restrict__ xg_f, const float* __restrict__ xg_b,
    const __half* __restrict__ whh16_f, const __half* __restrict__ whh16_b,
    fpp bhh_f, fpp bhh_b,
    const float* __restrict__ hprev, float* __restrict__ hnext,
    __half* __restrict__ seq, int step)
{
  const int dir = blockIdx.z;
  const float* __restrict__ xg = dir ? xg_b : xg_f;
  const __half* __restrict__ Whh = dir ? whh16_b : whh16_f;
  fpp bhh = dir ? bhh_b : bhh_f;
  const int t_out = dir ? (NT - 1 - step) : step;
  const int t_in  = dir ? (NT - step) : (step - 1);   // only used when step>0
  const int dcol = dir * NH;
  const int bm = blockIdx.x * 64, bn = blockIdx.y * 64;
  const int tid = threadIdx.x;
  const int wave = tid >> 6, lane = tid & 63;
  const int lm = lane & 15, quad = lane >> 4;

  __shared__ __half As[64 * 40];       // 64 rows x 32 k, stride 40
  __shared__ __half Bs[3 * 64 * 40];   // 3 gates x 64 n x 32 k

  floatx4 acc[3][4];
#pragma unroll
  for (int g = 0; g < 3; g++)
#pragma unroll
    for (int nt = 0; nt < 4; nt++) acc[g][nt] = (floatx4){0.f, 0.f, 0.f, 0.f};

  if (step > 0) {
    const int arow = tid >> 2, ak = (tid & 3) * 8;
    for (int k0 = 0; k0 < NH; k0 += 32) {
      __syncthreads();
      *(float4*)&As[arow * 40 + ak] =
        *(const float4*)&seq[((size_t)(bm + arow) * NT + t_in) * ND + dcol + k0 + ak];
#pragma unroll
      for (int i = 0; i < 3; i++) {
        int e = tid + i * 256;
        int g = e >> 8, rem = e & 255;
        int nr = rem >> 2, bk = (rem & 3) * 8;
        *(float4*)&Bs[(g * 64 + nr) * 40 + bk] =
          *(const float4*)&Whh[(size_t)(g * NH + bn + nr) * NH + k0 + bk];
      }
      __syncthreads();
      half8 af = *(const half8*)&As[(wave * 16 + lm) * 40 + quad * 8];
#pragma unroll
      for (int g = 0; g < 3; g++)
#pragma unroll
        for (int nt = 0; nt < 4; nt++) {
          half8 bf = *(const half8*)&Bs[(g * 64 + nt * 16 + lm) * 40 + quad * 8];
          acc[g][nt] = __builtin_amdgcn_mfma_f32_16x16x32_f16(af, bf, acc[g][nt], 0, 0, 0);
        }
    }
  }

  // epilogue: gates + state update. C layout: col=lane&15, row=quad*4+reg.
#pragma unroll
  for (int nt = 0; nt < 4; nt++) {
    int n = bn + nt * 16 + lm;
    float br = bhh[n], bz = bhh[NH + n], bnv = bhh[2 * NH + n];
#pragma unroll
    for (int r = 0; r < 4; r++) {
      int m = bm + wave * 16 + quad * 4 + r;
      float ghr = acc[0][nt][r] + br;
      float ghz = acc[1][nt][r] + bz;
      float ghn = acc[2][nt][r] + bnv;
      float xr = xg[(size_t)m * NG + n];
      float xz = xg[(size_t)m * NG + NH + n];
      float xn = xg[(size_t)m * NG + 2 * NH + n];
      float rg = 1.f / (1.f + __expf(-(xr + ghr)));
      float zg = 1.f / (1.f + __expf(-(xz + ghz)));
      float nn = tanhf(xn + rg * ghn);
      float hp = (step == 0) ? 0.f : hprev[(size_t)m * ND + dcol + n];
      float hv = (1.f - zg) * nn + zg * hp;
      hnext[(size_t)m * ND + dcol + n] = hv;
      seq[((size_t)m * NT + t_out) * ND + dcol + n] = __float2half(hv);
    }
  }
}

// ---------------------------------------------------------------------------
// Attention scores via MFMA: one pass, no atomics. Block = 64 rows.
// acc over all 16 n-tiles (N=256) held in registers.
// ---------------------------------------------------------------------------
__global__ __launch_bounds__(256) void attn_score_mfma(
    const __half* __restrict__ seq, const __half* __restrict__ w116,
    fpp b1, fpp W2, float* __restrict__ scores)
{
  const int bm = blockIdx.x * 64;
  const int tid = threadIdx.x;
  const int wave = tid >> 6, lane = tid & 63;
  const int lm = lane & 15, quad = lane >> 4;

  __shared__ __half As[64 * 40];
  __shared__ __half Bs[256 * 40];

  floatx4 acc[16];
#pragma unroll
  for (int nt = 0; nt < 16; nt++) acc[nt] = (floatx4){0.f, 0.f, 0.f, 0.f};

  const int arow = tid >> 2, ak = (tid & 3) * 8;
  for (int k0 = 0; k0 < ND; k0 += 32) {
    __syncthreads();
    *(float4*)&As[arow * 40 + ak] =
      *(const float4*)&seq[(size_t)(bm + arow) * ND + k0 + ak];
#pragma unroll
    for (int i = 0; i < 4; i++) {
      int e = tid + i * 256;
      int nr = e >> 2, bk = (e & 3) * 8;
      *(float4*)&Bs[nr * 40 + bk] =
        *(const float4*)&w116[(size_t)nr * ND + k0 + bk];
    }
    __syncthreads();
    half8 af = *(const half8*)&As[(wave * 16 + lm) * 40 + quad * 8];
#pragma unroll
    for (int nt = 0; nt < 16; nt++) {
      half8 bf = *(const half8*)&Bs[(nt * 16 + lm) * 40 + quad * 8];
      acc[nt] = __builtin_amdgcn_mfma_f32_16x16x32_f16(af, bf, acc[nt], 0, 0, 0);
    }
  }

  float rs[4] = {0.f, 0.f, 0.f, 0.f};
#pragma unroll
  for (int nt = 0; nt < 16; nt++) {
    int n = nt * 16 + lm;
    float b1v = b1[n], w2v = W2[n];
#pragma unroll
    for (int r = 0; r < 4; r++)
      rs[r] += tanhf(acc[nt][r] + b1v) * w2v;
  }
#pragma unroll
  for (int r = 0; r < 4; r++) {
    rs[r] += __shfl_xor(rs[r], 1);
    rs[r] += __shfl_xor(rs[r], 2);
    rs[r] += __shfl_xor(rs[r], 4);
    rs[r] += __shfl_xor(rs[r], 8);
  }
  if (lm == 0) {
#pragma unroll
    for (int r = 0; r < 4; r++)
      scores[bm + wave * 16 + quad * 4 + r] = rs[r];
  }
}

__global__ void softmax_t(float* __restrict__ s)
{
  int b = blockIdx.x, lane = threadIdx.x;
  float v = (lane < NT) ? s[(size_t)b * NT + lane] : -1e30f;
  float m = v;
#pragma unroll
  for (int off = 32; off >= 1; off >>= 1) m = fmaxf(m, __shfl_xor(m, off));
  float e = (lane < NT) ? __expf(v - m) : 0.f;
  float sum = e;
#pragma unroll
  for (int off = 32; off >= 1; off >>= 1) sum += __shfl_xor(sum, off);
  if (lane < NT) s[(size_t)b * NT + lane] = e / sum;
}

__global__ void context_c(const __half* __restrict__ seq,
                          const float* __restrict__ w, float* __restrict__ c)
{
  int idx = blockIdx.x * 256 + threadIdx.x;  // NB*64 groups of 8 cols
  int b = idx >> 6, d8 = (idx & 63) * 8;
  float s[8] = {};
  for (int t = 0; t < NT; t++) {
    float wt = w[(size_t)b * NT + t];
    half8 v = *(const half8*)&seq[((size_t)b * NT + t) * ND + d8];
#pragma unroll
    for (int i = 0; i < 8; i++) s[i] += wt * (float)v[i];
  }
  float* cp = c + (size_t)b * ND + d8;
#pragma unroll
  for (int i = 0; i < 8; i++) cp[i] = s[i];
}

// ---------------------------------------------------------------------------
// Fused joints projection + forward kinematics. One wave per (b,t).
// ---------------------------------------------------------------------------
__constant__ float c_lower[6] = {-3.1416f, -1.5708f, -3.1416f, -2.6f, -1.5708f, -1.2f};
__constant__ float c_upper[6] = { 3.1416f,  1.5708f,  3.1416f,  0.1f,  1.5708f,  1.2f};

__global__ __launch_bounds__(256) void joints_fk(
    const __half* __restrict__ seq, const float* __restrict__ c,
    fpp jW, fpp jb, float* __restrict__ out)
{
  __shared__ float w[6 * ND];
  const int tid = threadIdx.x;
#pragma unroll
  for (int i = 0; i < 12; i++) w[tid + i * 256] = jW[tid + i * 256];
  __syncthreads();

  const int wave = tid >> 6, lane = tid & 63;
  const int bt = blockIdx.x * 4 + wave;
  const int b = bt / NT;
  const int d0 = lane * 8;

  half8 hv = *(const half8*)&seq[(size_t)bt * ND + d0];
  float xv[8];
#pragma unroll
  for (int i = 0; i < 8; i++)
    xv[i] = (float)hv[i] + c[(size_t)b * ND + d0 + i];

  float jnt[6];
#pragma unroll
  for (int j = 0; j < 6; j++) {
    float p = 0.f;
#pragma unroll
    for (int i = 0; i < 8; i++) p = fmaf(xv[i], w[j * ND + d0 + i], p);
#pragma unroll
    for (int off = 32; off >= 1; off >>= 1) p += __shfl_xor(p, off);
    jnt[j] = p + jb[j];
  }

  float th[6];
#pragma unroll
  for (int j = 0; j < 6; j++)
    th[j] = jnt[j] * (c_upper[j] - c_lower[j]) + c_lower[j];

  float c0x = 1.f, c0y = 0.f, c0z = 0.f;
  float c1x = 0.f, c1y = 1.f, c1z = 0.f;
  float c2x = 0.f, c2y = 0.f, c2z = 1.f;
  float px = 0.f, py = 0.f, pz = 0.1f;
  float s, cc, tx_, ty_, tz_, ux_, uy_, uz_;

  // rotZ(th0)
  s = sinf(th[0]); cc = cosf(th[0]);
  tx_ = cc * c0x + s * c1x; ty_ = cc * c0y + s * c1y; tz_ = cc * c0z + s * c1z;
  ux_ = -s * c0x + cc * c1x; uy_ = -s * c0y + cc * c1y; uz_ = -s * c0z + cc * c1z;
  c0x = tx_; c0y = ty_; c0z = tz_; c1x = ux_; c1y = uy_; c1z = uz_;

  float shx = px, shy = py, shz = pz;  // shoulder2
  // rotX(th1)
  s = sinf(th[1]); cc = cosf(th[1]);
  tx_ = cc * c1x + s * c2x; ty_ = cc * c1y + s * c2y; tz_ = cc * c1z + s * c2z;
  ux_ = -s * c1x + cc * c2x; uy_ = -s * c1y + cc * c2y; uz_ = -s * c1z + cc * c2z;
  c1x = tx_; c1y = ty_; c1z = tz_; c2x = ux_; c2y = uy_; c2z = uz_;

  // rotY(th2)
  s = sinf(th[2]); cc = cosf(th[2]);
  tx_ = cc * c0x - s * c2x; ty_ = cc * c0y - s * c2y; tz_ = cc * c0z - s * c2z;
  ux_ = s * c0x + cc * c2x; uy_ = s * c0y + cc * c2y; uz_ = s * c0z + cc * c2z;
  c0x = tx_; c0y = ty_; c0z = tz_; c2x = ux_; c2y = uy_; c2z = uz_;

  // joint3 offset -> forearm
  px -= 0.25f * c1x; py -= 0.25f * c1y; pz -= 0.25f * c1z;
  float fox = px, foy = py, foz = pz;
  // rotX(th3)
  s = sinf(th[3]); cc = cosf(th[3]);
  tx_ = cc * c1x + s * c2x; ty_ = cc * c1y + s * c2y; tz_ = cc * c1z + s * c2z;
  ux_ = -s * c1x + cc * c2x; uy_ = -s * c1y + cc * c2y; uz_ = -s * c1z + cc * c2z;
  c1x = tx_; c1y = ty_; c1z = tz_; c2x = ux_; c2y = uy_; c2z = uz_;

  // rotY(th4)
  s = sinf(th[4]); cc = cosf(th[4]);
  tx_ = cc * c0x - s * c2x; ty_ = cc * c0y - s * c2y; tz_ = cc * c0z - s * c2z;
  ux_ = s * c0x + cc * c2x; uy_ = s * c0y + cc * c2y; uz_ = s * c0z + cc * c2z;
  c0x = tx_; c0y = ty_; c0z = tz_; c2x = ux_; c2y = uy_; c2z = uz_;

  // joint5 offset -> wrist
  px -= 0.25f * c1x; py -= 0.25f * c1y; pz -= 0.25f * c1z;
  float wx = px, wy = py, wz = pz;
  // rotX(th5)
  s = sinf(th[5]); cc = cosf(th[5]);
  tx_ = cc * c1x + s * c2x; ty_ = cc * c1y + s * c2y; tz_ = cc * c1z + s * c2z;
  ux_ = -s * c1x + cc * c2x; uy_ = -s * c1y + cc * c2y; uz_ = -s * c1z + cc * c2z;
  c1x = tx_; c1y = ty_; c1z = tz_; c2x = ux_; c2y = uy_; c2z = uz_;

  float f1x = wx - 0.08f * c1x + 0.02f * c2x;
  float f1y = wy - 0.08f * c1y + 0.02f * c2y;
  float f1z = wz - 0.08f * c1z + 0.02f * c2z;
  float f4x = wx - 0.08f * c1x - 0.02f * c2x;
  float f4y = wy - 0.08f * c1y - 0.02f * c2y;
  float f4z = wz - 0.08f * c1z - 0.02f * c2z;

  float dsx = shx - fox, dsy = shy - foy, dsz = shz - foz;
  float dwx = wx - fox, dwy = wy - foy, dwz = wz - foz;
  float bodyL = 0.5f * (sqrtf(dsx * dsx + dsy * dsy + dsz * dsz) +
                        sqrtf(dwx * dwx + dwy * dwy + dwz * dwz));
  float inv = 1.f / bodyL;

  float rel[9];
  rel[0] = (wx - shx) * inv; rel[1] = (wy - shy) * inv; rel[2] = (wz - shz) * inv;
  rel[3] = (f1x - shx) * inv; rel[4] = (f1y - shy) * inv; rel[5] = (f1z - shz) * inv;
  rel[6] = (f4x - shx) * inv; rel[7] = (f4y - shy) * inv; rel[8] = (f4z - shz) * inv;

  if (lane < 9) out[(size_t)bt * 9 + lane] = rel[lane];
}

// ---------------------------------------------------------------------------
extern "C" void kernel_launch(void* const* d_in, const int* in_sizes, int n_in,
                              void* d_out, int out_size, void* d_ws, size_t ws_size,
                              hipStream_t stream)
{
  fpp z     = (fpp)d_in[0];
  fpp W_fc  = (fpp)d_in[1];
  fpp b_fc  = (fpp)d_in[2];
  fpp bn_g  = (fpp)d_in[3];
  fpp bn_b  = (fpp)d_in[4];
  fpp Wih_f = (fpp)d_in[5];
  fpp Whh_f = (fpp)d_in[6];
  fpp bih_f = (fpp)d_in[7];
  fpp bhh_f = (fpp)d_in[8];
  fpp Wih_b = (fpp)d_in[9];
  fpp Whh_b = (fpp)d_in[10];
  fpp bih_b = (fpp)d_in[11];
  fpp bhh_b = (fpp)d_in[12];
  fpp aW1   = (fpp)d_in[13];
  fpp ab1   = (fpp)d_in[14];
  fpp aW2   = (fpp)d_in[15];
  fpp jW    = (fpp)d_in[16];
  fpp jb    = (fpp)d_in[17];

  // fp32 region (~29.9 MB), fp16 seq (~126 MB), fp16 weights (~1.1 MB).
  float* ws     = (float*)d_ws;
  float* h      = ws;                        // 2048*512
  float* xg_f   = h + 1048576;               // 2048*768
  float* xg_b   = xg_f + 1572864;            // 2048*768
  float* scale  = xg_b + 1572864;            // 512
  float* shift  = scale + 512;               // 512
  float* scores = shift + 512;               // 2048*60
  float* cbuf   = scores + 122880;           // 2048*512
  float* hst0   = cbuf + 1048576;            // 2048*512
  float* hst1   = hst0 + 1048576;            // 2048*512
  __half* gseq    = (__half*)(hst1 + 1048576);   // 2048*60*512 fp16
  __half* whh16_f = gseq + 62914560;             // 768*256
  __half* whh16_b = whh16_f + 196608;            // 768*256
  __half* w116    = whh16_b + 196608;            // 256*512

  // 0. weight conversion fp32->fp16 (524288 elements)
  convert_w<<<2048, 256, 0, stream>>>(Whh_f, Whh_b, aW1, whh16_f, whh16_b, w116);
  // 1. fc: h0 = z @ W_fc^T + b_fc
  gemm_fc<<<dim3(32, 8), 256, 0, stream>>>(z, W_fc, b_fc, h,
                                           NB, ND, NDL, NDL, NDL, ND);
  // 2. batchnorm (training stats) + leaky relu, in place
  bn_stats<<<16, 256, 0, stream>>>(h, bn_g, bn_b, scale, shift);
  bn_lrelu<<<4096, 256, 0, stream>>>(h, scale, shift);
  // 3. time-invariant input projections (computed ONCE)
  gemm_fc<<<dim3(32, 12), 256, 0, stream>>>(h, Wih_f, bih_f, xg_f,
                                            NB, NG, ND, ND, ND, NG);
  gemm_fc<<<dim3(32, 12), 256, 0, stream>>>(h, Wih_b, bih_b, xg_b,
                                            NB, NG, ND, ND, ND, NG);
  // 4. GRU recurrence via MFMA, both directions per launch
  for (int s = 0; s < NT; s++) {
    float* hp = (s & 1) ? hst1 : hst0;
    float* hn = (s & 1) ? hst0 : hst1;
    gru_step_mfma<<<dim3(32, 4, 2), 256, 0, stream>>>(
        xg_f, xg_b, whh16_f, whh16_b, bhh_f, bhh_b, hp, hn, gseq, s);
  }
  // 5. attention (single-pass MFMA, no atomics)
  attn_score_mfma<<<1920, 256, 0, stream>>>(gseq, w116, ab1, aW2, scores);
  softmax_t<<<NB, 64, 0, stream>>>(scores);
  context_c<<<512, 256, 0, stream>>>(gseq, scores, cbuf);
  // 6. joints projection + forward kinematics, fused
  joints_fk<<<30720, 256, 0, stream>>>(gseq, cbuf, jW, jb, (float*)d_out);
}

// Round 7
// 1271.343 us; speedup vs baseline: 2.9640x; 1.1030x over previous
//
#include <hip/hip_runtime.h>
#include <hip/hip_fp16.h>

#define NB 2048
#define NT 60
#define NDL 100
#define ND 512
#define NH 256
#define NG 768

typedef const float* __restrict__ fpp;
typedef _Float16 half8 __attribute__((ext_vector_type(8)));
typedef float floatx4 __attribute__((ext_vector_type(4)));

__device__ __forceinline__ float fast_sig(float x) {
  return 1.f / (1.f + __expf(-x));
}
__device__ __forceinline__ float fast_tanh(float x) {
  float t = __expf(2.f * x);           // finite for |x| < 44; inputs are O(10)
  return (t - 1.f) / (t + 1.f);
}

// ---------------------------------------------------------------------------
// fp32 tiled GEMM (fc layer only, K=100): C = A*B^T + bias
// ---------------------------------------------------------------------------
__global__ __launch_bounds__(256) void gemm_fc(
    fpp A, fpp Bm, fpp bias, float* __restrict__ C,
    int M, int N, int K, int lda, int ldb, int ldc)
{
  __shared__ float As[16][68];
  __shared__ float Bs[16][68];
  const int bm = blockIdx.x * 64, bn = blockIdx.y * 64;
  const int tid = threadIdx.x;
  const int tx = tid & 15, ty = tid >> 4;
  float acc[4][4] = {};
  for (int k0 = 0; k0 < K; k0 += 16) {
#pragma unroll
    for (int i = 0; i < 4; i++) {
      int e = tid + i * 256;
      int m = e >> 4, k = e & 15;
      As[k][m] = (k0 + k < K) ? A[(size_t)(bm + m) * lda + k0 + k] : 0.f;
      Bs[k][m] = (k0 + k < K) ? Bm[(size_t)(bn + m) * ldb + k0 + k] : 0.f;
    }
    __syncthreads();
#pragma unroll
    for (int kk = 0; kk < 16; kk++) {
      float4 av = *(const float4*)&As[kk][ty * 4];
      float4 bv = *(const float4*)&Bs[kk][tx * 4];
      float a_[4] = {av.x, av.y, av.z, av.w};
      float b_[4] = {bv.x, bv.y, bv.z, bv.w};
#pragma unroll
      for (int i = 0; i < 4; i++)
#pragma unroll
        for (int j = 0; j < 4; j++)
          acc[i][j] = fmaf(a_[i], b_[j], acc[i][j]);
    }
    __syncthreads();
  }
#pragma unroll
  for (int i = 0; i < 4; i++) {
    int m = bm + ty * 4 + i;
#pragma unroll
    for (int j = 0; j < 4; j++) {
      int n = bn + tx * 4 + j;
      C[(size_t)m * ldc + n] = acc[i][j] + bias[n];
    }
  }
}

// ---------------------------------------------------------------------------
// BatchNorm batch statistics -> per-column scale/shift
// ---------------------------------------------------------------------------
__global__ __launch_bounds__(256) void bn_stats(
    const float* __restrict__ h0, fpp g, fpp b,
    float* __restrict__ scale, float* __restrict__ shift)
{
  const int cl = threadIdx.x & 31;
  const int col = blockIdx.x * 32 + cl;
  const int row0 = threadIdx.x >> 5;
  float s1 = 0.f, s2 = 0.f;
  for (int r = row0; r < NB; r += 8) {
    float v = h0[(size_t)r * ND + col];
    s1 += v; s2 += v * v;
  }
  __shared__ float l1[8][33], l2[8][33];
  l1[row0][cl] = s1;
  l2[row0][cl] = s2;
  __syncthreads();
  if (row0 == 0) {
#pragma unroll
    for (int r = 1; r < 8; r++) { s1 += l1[r][cl]; s2 += l2[r][cl]; }
    float mu = s1 / NB;
    float var = s2 / NB - mu * mu;
    float sc = g[col] * rsqrtf(var + 1e-5f);
    scale[col] = sc;
    shift[col] = b[col] - mu * sc;
  }
}

// bn + leaky relu, writing fp16 (consumed only by fp16 MFMA xg projections)
__global__ void bn_lrelu_h16(const float* __restrict__ h0,
                             const float* __restrict__ scale,
                             const float* __restrict__ shift,
                             __half* __restrict__ h16g)
{
  int idx = blockIdx.x * 256 + threadIdx.x;
  int d = idx & (ND - 1);
  float v = h0[idx] * scale[d] + shift[d];
  h16g[idx] = __float2half(v >= 0.f ? v : 0.2f * v);
}

// ---------------------------------------------------------------------------
// One-time weight conversions fp32 -> fp16
// ---------------------------------------------------------------------------
__global__ void convert_w(fpp whf, fpp whb, fpp w1, fpp wif, fpp wib,
                          __half* __restrict__ o_whf, __half* __restrict__ o_whb,
                          __half* __restrict__ o_w1, __half* __restrict__ o_wif,
                          __half* __restrict__ o_wib)
{
  int idx = blockIdx.x * 256 + threadIdx.x;  // 0 .. 1310719
  if (idx < 196608) o_whf[idx] = __float2half(whf[idx]);
  else if (idx < 393216) o_whb[idx - 196608] = __float2half(whb[idx - 196608]);
  else if (idx < 524288) o_w1[idx - 393216] = __float2half(w1[idx - 393216]);
  else if (idx < 917504) o_wif[idx - 524288] = __float2half(wif[idx - 524288]);
  else o_wib[idx - 917504] = __float2half(wib[idx - 917504]);
}

// ---------------------------------------------------------------------------
// fp16 MFMA GEMM (xg projections): C[m][n] = A[m][:]·B[n][:] + bias[n]
// M=2048 (grid.x*64), K multiple of 32. C fp32.
// ---------------------------------------------------------------------------
__global__ __launch_bounds__(256) void gemm16(
    const __half* __restrict__ A, const __half* __restrict__ Bm,
    fpp bias, float* __restrict__ C, int N, int K)
{
  __shared__ __half As[64 * 40];
  __shared__ __half Bs[64 * 40];
  const int bm = blockIdx.x * 64, bn = blockIdx.y * 64;
  const int tid = threadIdx.x;
  const int wave = tid >> 6, lane = tid & 63;
  const int lm = lane & 15, quad = lane >> 4;
  floatx4 acc[4];
#pragma unroll
  for (int nt = 0; nt < 4; nt++) acc[nt] = (floatx4){0.f, 0.f, 0.f, 0.f};

  const int row = tid >> 2, kc = tid & 3;
  for (int k0 = 0; k0 < K; k0 += 32) {
    __syncthreads();
    *(float4*)&As[row * 40 + kc * 8] =
      *(const float4*)&A[(size_t)(bm + row) * K + k0 + kc * 8];
    *(float4*)&Bs[row * 40 + kc * 8] =
      *(const float4*)&Bm[(size_t)(bn + row) * K + k0 + kc * 8];
    __syncthreads();
    half8 af = *(const half8*)&As[(wave * 16 + lm) * 40 + quad * 8];
#pragma unroll
    for (int nt = 0; nt < 4; nt++) {
      half8 bf = *(const half8*)&Bs[(nt * 16 + lm) * 40 + quad * 8];
      acc[nt] = __builtin_amdgcn_mfma_f32_16x16x32_f16(af, bf, acc[nt], 0, 0, 0);
    }
  }
#pragma unroll
  for (int nt = 0; nt < 4; nt++) {
    int n = bn + nt * 16 + lm;
    float bv = bias[n];
#pragma unroll
    for (int r = 0; r < 4; r++) {
      int m = bm + wave * 16 + quad * 4 + r;
      C[(size_t)m * N + n] = acc[nt][r] + bv;
    }
  }
}

// ---------------------------------------------------------------------------
// PERSISTENT GRU: one launch for the whole recurrence.
// Block = 32 batch rows x one direction (grid 128). No grid sync needed:
// batch rows are independent across time. h state in registers + LDS fp16
// copy for next step's MFMA A-fragments; Whh streamed from L2; xg preloaded
// once into registers (time-invariant).
// ---------------------------------------------------------------------------
__global__ __launch_bounds__(256, 1) void gru_persistent(
    const float* __restrict__ xg_f, const float* __restrict__ xg_b,
    const __half* __restrict__ whh16_f, const __half* __restrict__ whh16_b,
    fpp bhh_f, fpp bhh_b, __half* __restrict__ seq)
{
  const int dir = blockIdx.x >> 6;
  const int tile = blockIdx.x & 63;
  const int bm = tile * 32;
  const float* __restrict__ xg = dir ? xg_b : xg_f;
  const __half* __restrict__ Whh = dir ? whh16_b : whh16_f;
  fpp bhh = dir ? bhh_b : bhh_f;
  const int dcol = dir * NH;
  const int tid = threadIdx.x;
  const int wave = tid >> 6, lane = tid & 63;
  const int lm = lane & 15, quad = lane >> 4;

  __shared__ __half h16[32 * 264];

  // step-invariant B fragment pointers
  const __half* bp[3][4];
#pragma unroll
  for (int g = 0; g < 3; g++)
#pragma unroll
    for (int c = 0; c < 4; c++)
      bp[g][c] = Whh + (size_t)(g * NH + (wave * 4 + c) * 16 + lm) * NH + quad * 8;

  // preload xg + biases for this thread's fixed (m,n) positions
  float xr_[4][2][4], xz_[4][2][4], xn_[4][2][4];
  float br_[4], bz_[4], bn_[4];
#pragma unroll
  for (int c = 0; c < 4; c++) {
    int n = (wave * 4 + c) * 16 + lm;
    br_[c] = bhh[n]; bz_[c] = bhh[NH + n]; bn_[c] = bhh[2 * NH + n];
#pragma unroll
    for (int mt = 0; mt < 2; mt++)
#pragma unroll
      for (int r = 0; r < 4; r++) {
        int m = bm + mt * 16 + quad * 4 + r;
        const float* xp = xg + (size_t)m * NG + n;
        xr_[c][mt][r] = xp[0];
        xz_[c][mt][r] = xp[NH];
        xn_[c][mt][r] = xp[2 * NH];
      }
  }

  float hp[4][2][4];
#pragma unroll
  for (int c = 0; c < 4; c++)
#pragma unroll
    for (int mt = 0; mt < 2; mt++)
#pragma unroll
      for (int r = 0; r < 4; r++) hp[c][mt][r] = 0.f;

  const int arow0 = lm * 264 + quad * 8;
  const int hbase = (quad * 4) * 264 + wave * 64 + lm;

  for (int step = 0; step < NT; step++) {
    const int t_out = dir ? (NT - 1 - step) : step;
    floatx4 acc[3][4][2];
#pragma unroll
    for (int g = 0; g < 3; g++)
#pragma unroll
      for (int c = 0; c < 4; c++)
#pragma unroll
        for (int mt = 0; mt < 2; mt++)
          acc[g][c][mt] = (floatx4){0.f, 0.f, 0.f, 0.f};

    if (step > 0) {
#pragma unroll
      for (int k0 = 0; k0 < NH; k0 += 32) {
        half8 a0 = *(const half8*)&h16[arow0 + k0];
        half8 a1 = *(const half8*)&h16[arow0 + 16 * 264 + k0];
#pragma unroll
        for (int g = 0; g < 3; g++)
#pragma unroll
          for (int c = 0; c < 4; c++) {
            half8 bf = *(const half8*)(bp[g][c] + k0);
            acc[g][c][0] = __builtin_amdgcn_mfma_f32_16x16x32_f16(a0, bf, acc[g][c][0], 0, 0, 0);
            acc[g][c][1] = __builtin_amdgcn_mfma_f32_16x16x32_f16(a1, bf, acc[g][c][1], 0, 0, 0);
          }
      }
      __syncthreads();  // all h16 reads done before overwrite
    }

    size_t sbase = ((size_t)(bm + quad * 4) * NT + t_out) * ND + dcol + wave * 64 + lm;
#pragma unroll
    for (int c = 0; c < 4; c++)
#pragma unroll
      for (int mt = 0; mt < 2; mt++)
#pragma unroll
        for (int r = 0; r < 4; r++) {
          float rg = fast_sig(xr_[c][mt][r] + acc[0][c][mt][r] + br_[c]);
          float zg = fast_sig(xz_[c][mt][r] + acc[1][c][mt][r] + bz_[c]);
          float nn = fast_tanh(xn_[c][mt][r] + rg * (acc[2][c][mt][r] + bn_[c]));
          float hv = (1.f - zg) * nn + zg * hp[c][mt][r];
          hp[c][mt][r] = hv;
          __half hh = __float2half(hv);
          h16[hbase + c * 16 + (mt * 16 + r) * 264] = hh;
          seq[sbase + c * 16 + (size_t)(mt * 16 + r) * (NT * ND)] = hh;
        }
    __syncthreads();  // h16 complete before next step's reads
  }
}

// ---------------------------------------------------------------------------
// Attention scores via MFMA, M=128 rows/block, single pass, no atomics.
// ---------------------------------------------------------------------------
__global__ __launch_bounds__(256) void attn_score_mfma(
    const __half* __restrict__ seq, const __half* __restrict__ w116,
    fpp b1, fpp W2, float* __restrict__ scores)
{
  const int bm = blockIdx.x * 128;
  const int tid = threadIdx.x;
  const int wave = tid >> 6, lane = tid & 63;
  const int lm = lane & 15, quad = lane >> 4;

  __shared__ __half As[128 * 40];
  __shared__ __half Bs[256 * 40];

  floatx4 acc[2][16];
#pragma unroll
  for (int mt = 0; mt < 2; mt++)
#pragma unroll
    for (int nt = 0; nt < 16; nt++) acc[mt][nt] = (floatx4){0.f, 0.f, 0.f, 0.f};

  for (int k0 = 0; k0 < ND; k0 += 32) {
    __syncthreads();
#pragma unroll
    for (int i = 0; i < 2; i++) {
      int e = tid + i * 256;
      int row = e >> 2, kc = e & 3;
      *(float4*)&As[row * 40 + kc * 8] =
        *(const float4*)&seq[(size_t)(bm + row) * ND + k0 + kc * 8];
    }
#pragma unroll
    for (int i = 0; i < 4; i++) {
      int e = tid + i * 256;
      int row = e >> 2, kc = e & 3;
      *(float4*)&Bs[row * 40 + kc * 8] =
        *(const float4*)&w116[(size_t)row * ND + k0 + kc * 8];
    }
    __syncthreads();
    half8 a0 = *(const half8*)&As[((wave * 2 + 0) * 16 + lm) * 40 + quad * 8];
    half8 a1 = *(const half8*)&As[((wave * 2 + 1) * 16 + lm) * 40 + quad * 8];
#pragma unroll
    for (int nt = 0; nt < 16; nt++) {
      half8 bf = *(const half8*)&Bs[(nt * 16 + lm) * 40 + quad * 8];
      acc[0][nt] = __builtin_amdgcn_mfma_f32_16x16x32_f16(a0, bf, acc[0][nt], 0, 0, 0);
      acc[1][nt] = __builtin_amdgcn_mfma_f32_16x16x32_f16(a1, bf, acc[1][nt], 0, 0, 0);
    }
  }

  float rs[2][4] = {};
#pragma unroll
  for (int nt = 0; nt < 16; nt++) {
    int n = nt * 16 + lm;
    float b1v = b1[n], w2v = W2[n];
#pragma unroll
    for (int mt = 0; mt < 2; mt++)
#pragma unroll
      for (int r = 0; r < 4; r++)
        rs[mt][r] += fast_tanh(acc[mt][nt][r] + b1v) * w2v;
  }
#pragma unroll
  for (int mt = 0; mt < 2; mt++)
#pragma unroll
    for (int r = 0; r < 4; r++) {
      rs[mt][r] += __shfl_xor(rs[mt][r], 1);
      rs[mt][r] += __shfl_xor(rs[mt][r], 2);
      rs[mt][r] += __shfl_xor(rs[mt][r], 4);
      rs[mt][r] += __shfl_xor(rs[mt][r], 8);
    }
  if (lm == 0) {
#pragma unroll
    for (int mt = 0; mt < 2; mt++)
#pragma unroll
      for (int r = 0; r < 4; r++)
        scores[bm + (wave * 2 + mt) * 16 + quad * 4 + r] = rs[mt][r];
  }
}

__global__ void softmax_t(float* __restrict__ s)
{
  int b = blockIdx.x, lane = threadIdx.x;
  float v = (lane < NT) ? s[(size_t)b * NT + lane] : -1e30f;
  float m = v;
#pragma unroll
  for (int off = 32; off >= 1; off >>= 1) m = fmaxf(m, __shfl_xor(m, off));
  float e = (lane < NT) ? __expf(v - m) : 0.f;
  float sum = e;
#pragma unroll
  for (int off = 32; off >= 1; off >>= 1) sum += __shfl_xor(sum, off);
  if (lane < NT) s[(size_t)b * NT + lane] = e / sum;
}

__global__ void context_c(const __half* __restrict__ seq,
                          const float* __restrict__ w, float* __restrict__ c)
{
  int idx = blockIdx.x * 256 + threadIdx.x;  // NB*64 groups of 8 cols
  int b = idx >> 6, d8 = (idx & 63) * 8;
  float s[8] = {};
  for (int t = 0; t < NT; t++) {
    float wt = w[(size_t)b * NT + t];
    half8 v = *(const half8*)&seq[((size_t)b * NT + t) * ND + d8];
#pragma unroll
    for (int i = 0; i < 8; i++) s[i] += wt * (float)v[i];
  }
  float* cp = c + (size_t)b * ND + d8;
#pragma unroll
  for (int i = 0; i < 8; i++) cp[i] = s[i];
}

// ---------------------------------------------------------------------------
// Fused joints projection + forward kinematics. One wave per (b,t).
// ---------------------------------------------------------------------------
__constant__ float c_lower[6] = {-3.1416f, -1.5708f, -3.1416f, -2.6f, -1.5708f, -1.2f};
__constant__ float c_upper[6] = { 3.1416f,  1.5708f,  3.1416f,  0.1f,  1.5708f,  1.2f};

__global__ __launch_bounds__(256) void joints_fk(
    const __half* __restrict__ seq, const float* __restrict__ c,
    fpp jW, fpp jb, float* __restrict__ out)
{
  __shared__ float w[6 * ND];
  const int tid = threadIdx.x;
#pragma unroll
  for (int i = 0; i < 12; i++) w[tid + i * 256] = jW[tid + i * 256];
  __syncthreads();

  const int wave = tid >> 6, lane = tid & 63;
  const int bt = blockIdx.x * 4 + wave;
  const int b = bt / NT;
  const int d0 = lane * 8;

  half8 hv = *(const half8*)&seq[(size_t)bt * ND + d0];
  float xv[8];
#pragma unroll
  for (int i = 0; i < 8; i++)
    xv[i] = (float)hv[i] + c[(size_t)b * ND + d0 + i];

  float jnt[6];
#pragma unroll
  for (int j = 0; j < 6; j++) {
    float p = 0.f;
#pragma unroll
    for (int i = 0; i < 8; i++) p = fmaf(xv[i], w[j * ND + d0 + i], p);
#pragma unroll
    for (int off = 32; off >= 1; off >>= 1) p += __shfl_xor(p, off);
    jnt[j] = p + jb[j];
  }

  float th[6];
#pragma unroll
  for (int j = 0; j < 6; j++)
    th[j] = jnt[j] * (c_upper[j] - c_lower[j]) + c_lower[j];

  float c0x = 1.f, c0y = 0.f, c0z = 0.f;
  float c1x = 0.f, c1y = 1.f, c1z = 0.f;
  float c2x = 0.f, c2y = 0.f, c2z = 1.f;
  float px = 0.f, py = 0.f, pz = 0.1f;
  float s, cc, tx_, ty_, tz_, ux_, uy_, uz_;

  // rotZ(th0)
  s = sinf(th[0]); cc = cosf(th[0]);
  tx_ = cc * c0x + s * c1x; ty_ = cc * c0y + s * c1y; tz_ = cc * c0z + s * c1z;
  ux_ = -s * c0x + cc * c1x; uy_ = -s * c0y + cc * c1y; uz_ = -s * c0z + cc * c1z;
  c0x = tx_; c0y = ty_; c0z = tz_; c1x = ux_; c1y = uy_; c1z = uz_;

  float shx = px, shy = py, shz = pz;  // shoulder2
  // rotX(th1)
  s = sinf(th[1]); cc = cosf(th[1]);
  tx_ = cc * c1x + s * c2x; ty_ = cc * c1y + s * c2y; tz_ = cc * c1z + s * c2z;
  ux_ = -s * c1x + cc * c2x; uy_ = -s * c1y + cc * c2y; uz_ = -s * c1z + cc * c2z;
  c1x = tx_; c1y = ty_; c1z = tz_; c2x = ux_; c2y = uy_; c2z = uz_;

  // rotY(th2)
  s = sinf(th[2]); cc = cosf(th[2]);
  tx_ = cc * c0x - s * c2x; ty_ = cc * c0y - s * c2y; tz_ = cc * c0z - s * c2z;
  ux_ = s * c0x + cc * c2x; uy_ = s * c0y + cc * c2y; uz_ = s * c0z + cc * c2z;
  c0x = tx_; c0y = ty_; c0z = tz_; c2x = ux_; c2y = uy_; c2z = uz_;

  // joint3 offset -> forearm
  px -= 0.25f * c1x; py -= 0.25f * c1y; pz -= 0.25f * c1z;
  float fox = px, foy = py, foz = pz;
  // rotX(th3)
  s = sinf(th[3]); cc = cosf(th[3]);
  tx_ = cc * c1x + s * c2x; ty_ = cc * c1y + s * c2y; tz_ = cc * c1z + s * c2z;
  ux_ = -s * c1x + cc * c2x; uy_ = -s * c1y + cc * c2y; uz_ = -s * c1z + cc * c2z;
  c1x = tx_; c1y = ty_; c1z = tz_; c2x = ux_; c2y = uy_; c2z = uz_;

  // rotY(th4)
  s = sinf(th[4]); cc = cosf(th[4]);
  tx_ = cc * c0x - s * c2x; ty_ = cc * c0y - s * c2y; tz_ = cc * c0z - s * c2z;
  ux_ = s * c0x + cc * c2x; uy_ = s * c0y + cc * c2y; uz_ = s * c0z + cc * c2z;
  c0x = tx_; c0y = ty_; c0z = tz_; c2x = ux_; c2y = uy_; c2z = uz_;

  // joint5 offset -> wrist
  px -= 0.25f * c1x; py -= 0.25f * c1y; pz -= 0.25f * c1z;
  float wx = px, wy = py, wz = pz;
  // rotX(th5)
  s = sinf(th[5]); cc = cosf(th[5]);
  tx_ = cc * c1x + s * c2x; ty_ = cc * c1y + s * c2y; tz_ = cc * c1z + s * c2z;
  ux_ = -s * c1x + cc * c2x; uy_ = -s * c1y + cc * c2y; uz_ = -s * c1z + cc * c2z;
  c1x = tx_; c1y = ty_; c1z = tz_; c2x = ux_; c2y = uy_; c2z = uz_;

  float f1x = wx - 0.08f * c1x + 0.02f * c2x;
  float f1y = wy - 0.08f * c1y + 0.02f * c2y;
  float f1z = wz - 0.08f * c1z + 0.02f * c2z;
  float f4x = wx - 0.08f * c1x - 0.02f * c2x;
  float f4y = wy - 0.08f * c1y - 0.02f * c2y;
  float f4z = wz - 0.08f * c1z - 0.02f * c2z;

  float dsx = shx - fox, dsy = shy - foy, dsz = shz - foz;
  float dwx = wx - fox, dwy = wy - foy, dwz = wz - foz;
  float bodyL = 0.5f * (sqrtf(dsx * dsx + dsy * dsy + dsz * dsz) +
                        sqrtf(dwx * dwx + dwy * dwy + dwz * dwz));
  float inv = 1.f / bodyL;

  float rel[9];
  rel[0] = (wx - shx) * inv; rel[1] = (wy - shy) * inv; rel[2] = (wz - shz) * inv;
  rel[3] = (f1x - shx) * inv; rel[4] = (f1y - shy) * inv; rel[5] = (f1z - shz) * inv;
  rel[6] = (f4x - shx) * inv; rel[7] = (f4y - shy) * inv; rel[8] = (f4z - shz) * inv;

  if (lane < 9) out[(size_t)bt * 9 + lane] = rel[lane];
}

// ---------------------------------------------------------------------------
extern "C" void kernel_launch(void* const* d_in, const int* in_sizes, int n_in,
                              void* d_out, int out_size, void* d_ws, size_t ws_size,
                              hipStream_t stream)
{
  fpp z     = (fpp)d_in[0];
  fpp W_fc  = (fpp)d_in[1];
  fpp b_fc  = (fpp)d_in[2];
  fpp bn_g  = (fpp)d_in[3];
  fpp bn_b  = (fpp)d_in[4];
  fpp Wih_f = (fpp)d_in[5];
  fpp Whh_f = (fpp)d_in[6];
  fpp bih_f = (fpp)d_in[7];
  fpp bhh_f = (fpp)d_in[8];
  fpp Wih_b = (fpp)d_in[9];
  fpp Whh_b = (fpp)d_in[10];
  fpp bih_b = (fpp)d_in[11];
  fpp bhh_b = (fpp)d_in[12];
  fpp aW1   = (fpp)d_in[13];
  fpp ab1   = (fpp)d_in[14];
  fpp aW2   = (fpp)d_in[15];
  fpp jW    = (fpp)d_in[16];
  fpp jb    = (fpp)d_in[17];

  float* ws     = (float*)d_ws;
  float* h0     = ws;                        // 2048*512 fp32
  float* xg_f   = h0 + 1048576;              // 2048*768 fp32
  float* xg_b   = xg_f + 1572864;            // 2048*768 fp32
  float* scale  = xg_b + 1572864;            // 512
  float* shift  = scale + 512;               // 512
  float* scores = shift + 512;               // 2048*60
  float* cbuf   = scores + 122880;           // 2048*512
  __half* gseq    = (__half*)(cbuf + 1048576);   // 2048*60*512 fp16 (126 MB)
  __half* whh16_f = gseq + 62914560;             // 768*256
  __half* whh16_b = whh16_f + 196608;            // 768*256
  __half* w116    = whh16_b + 196608;            // 256*512
  __half* wih16_f = w116 + 131072;               // 768*512
  __half* wih16_b = wih16_f + 393216;            // 768*512
  __half* h16g    = wih16_b + 393216;            // 2048*512

  // 0. weight conversions fp32->fp16
  convert_w<<<5120, 256, 0, stream>>>(Whh_f, Whh_b, aW1, Wih_f, Wih_b,
                                      whh16_f, whh16_b, w116, wih16_f, wih16_b);
  // 1. fc: h0 = z @ W_fc^T + b_fc (fp32, K=100)
  gemm_fc<<<dim3(32, 8), 256, 0, stream>>>(z, W_fc, b_fc, h0,
                                           NB, ND, NDL, NDL, NDL, ND);
  // 2. batchnorm (training stats) + leaky relu -> fp16 h
  bn_stats<<<16, 256, 0, stream>>>(h0, bn_g, bn_b, scale, shift);
  bn_lrelu_h16<<<4096, 256, 0, stream>>>(h0, scale, shift, h16g);
  // 3. time-invariant input projections via MFMA (computed ONCE)
  gemm16<<<dim3(32, 12), 256, 0, stream>>>(h16g, wih16_f, bih_f, xg_f, NG, ND);
  gemm16<<<dim3(32, 12), 256, 0, stream>>>(h16g, wih16_b, bih_b, xg_b, NG, ND);
  // 4. ENTIRE GRU recurrence: one persistent launch, both directions
  gru_persistent<<<128, 256, 0, stream>>>(xg_f, xg_b, whh16_f, whh16_b,
                                          bhh_f, bhh_b, gseq);
  // 5. attention
  attn_score_mfma<<<960, 256, 0, stream>>>(gseq, w116, ab1, aW2, scores);
  softmax_t<<<NB, 64, 0, stream>>>(scores);
  context_c<<<512, 256, 0, stream>>>(gseq, scores, cbuf);
  // 6. joints projection + forward kinematics, fused
  joints_fk<<<30720, 256, 0, stream>>>(gseq, cbuf, jW, jb, (float*)d_out);
}